// Round 1
// 260.126 us; speedup vs baseline: 1.0130x; 1.0130x over previous
//
#include <hip/hip_runtime.h>

// Problem: B=128, N=65536, h=30.
// loss = sum_b sum_i ||gt[b] - (cand[b,i]+off[b,i])||^2  (argsort is a full
// permutation summed over afterwards -> irrelevant). RCNN passthrough.
// Output: RCNN_cls_result flat (B*N*2 floats) ++ loss (1 float).
//
// R1 lesson: same-address atomics serialize (~13ns each) -> block partials.
// R2 lesson: per-iter loop w/ bounds check = 3 loads in flight per wave ->
//   latency-bound at 1.9 TB/s. Fix: issue all 12 float4 loads up front.
// R3 lesson: __builtin_nontemporal_store needs a clang ext_vector type, not
//   HIP's float4 class.
// R4 (this round): VGPR_Count=32 proved the compiler re-sank the loads into
//   per-u groups (<=4 in flight) despite source order -> still latency-bound.
//   Also the 30-iter serial wave-uniform y-loop (~6k cyc) ran BEFORE any
//   stream load was issued. Fixes: (a) lane-parallel y load + shfl_xor
//   butterfly (1 latency instead of 30), (b) sched_barrier(0) after all 13
//   loads to pin them in flight (VGPR rise to ~64-72 is intentional).

typedef float v4f __attribute__((ext_vector_type(4)));

__global__ __launch_bounds__(256) void copy_and_loss_kernel(
    const v4f* __restrict__ cand,
    const v4f* __restrict__ off,
    const v4f* __restrict__ rcnn,
    v4f* __restrict__ out,
    const float* __restrict__ y,     // [B*h*2]
    float* __restrict__ partials,    // [gridDim.x]
    int n4, int log_row4, int h)
{
    constexpr int U = 4;
    const size_t base = (size_t)blockIdx.x * (256 * U);
    const int b = (int)(base >> log_row4);   // uniform per block (chunk < row)
    const int lane = threadIdx.x & 63;

    float acc = 0.f;
    if (base + 256 * U <= (size_t)n4) {      // uniform fast path (exact grid)
        // --- issue ALL loads before any consumer ---------------------------
        v4f c[U], o[U], r[U];
        #pragma unroll
        for (int u = 0; u < U; ++u) c[u] = cand[base + u * 256 + threadIdx.x];
        #pragma unroll
        for (int u = 0; u < U; ++u) o[u] = off[base + u * 256 + threadIdx.x];
        #pragma unroll
        for (int u = 0; u < U; ++u) r[u] = rcnn[base + u * 256 + threadIdx.x];

        // gt[b]: lane-parallel load (h=30 -> single iter), issued last so the
        // butterfly's wait drains everything exactly once.
        float gx = 0.f, gy = 0.f;
        {
            const float2* yb = (const float2*)y + (size_t)b * h;
            for (int i = lane; i < h; i += 64) { float2 v = yb[i]; gx += v.x; gy += v.y; }
        }

        // Pin the schedule: nothing (stores, FMAs, shuffles) may be hoisted
        // above this point, so all 13 loads are in flight per thread.
        __builtin_amdgcn_sched_barrier(0);

        #pragma unroll
        for (int s = 32; s > 0; s >>= 1) {
            gx += __shfl_xor(gx, s, 64);
            gy += __shfl_xor(gy, s, 64);
        }

        #pragma unroll
        for (int u = 0; u < U; ++u) {
            __builtin_nontemporal_store(r[u], &out[base + u * 256 + threadIdx.x]);
            float dx0 = gx - (c[u].x + o[u].x);
            float dy0 = gy - (c[u].y + o[u].y);
            float dx1 = gx - (c[u].z + o[u].z);
            float dy1 = gy - (c[u].w + o[u].w);
            acc += dx0*dx0 + dy0*dy0 + dx1*dx1 + dy1*dy1;
        }
    } else {                                  // tail (not taken for B=128,N=64K)
        float gx = 0.f, gy = 0.f;
        {
            const float2* yb = (const float2*)y + (size_t)b * h;
            for (int i = lane; i < h; i += 64) { float2 v = yb[i]; gx += v.x; gy += v.y; }
        }
        #pragma unroll
        for (int s = 32; s > 0; s >>= 1) {
            gx += __shfl_xor(gx, s, 64);
            gy += __shfl_xor(gy, s, 64);
        }
        #pragma unroll
        for (int u = 0; u < U; ++u) {
            size_t idx = base + u * 256 + threadIdx.x;
            if (idx < (size_t)n4) {
                v4f c = cand[idx], o = off[idx], r = rcnn[idx];
                __builtin_nontemporal_store(r, &out[idx]);
                float dx0 = gx - (c.x + o.x);
                float dy0 = gy - (c.y + o.y);
                float dx1 = gx - (c.z + o.z);
                float dy1 = gy - (c.w + o.w);
                acc += dx0*dx0 + dy0*dy0 + dx1*dx1 + dy1*dy1;
            }
        }
    }

    // wave-64 reduce, 4 waves -> LDS -> thread 0
    #pragma unroll
    for (int s = 32; s > 0; s >>= 1) acc += __shfl_down(acc, s, 64);
    __shared__ float lds[4];
    int l = threadIdx.x & 63, wid = threadIdx.x >> 6;
    if (l == 0) lds[wid] = acc;
    __syncthreads();
    if (threadIdx.x == 0)
        partials[blockIdx.x] = lds[0] + lds[1] + lds[2] + lds[3];
}

__global__ __launch_bounds__(256) void final_reduce_kernel(
    const float* __restrict__ partials, float* __restrict__ loss_slot, int n)
{
    float acc = 0.f;
    for (int i = threadIdx.x; i < n; i += 256) acc += partials[i];
    #pragma unroll
    for (int s = 32; s > 0; s >>= 1) acc += __shfl_down(acc, s, 64);
    __shared__ float lds[4];
    int lane = threadIdx.x & 63, wid = threadIdx.x >> 6;
    if (lane == 0) lds[wid] = acc;
    __syncthreads();
    if (threadIdx.x == 0)
        *loss_slot = lds[0] + lds[1] + lds[2] + lds[3];
}

extern "C" void kernel_launch(void* const* d_in, const int* in_sizes, int n_in,
                              void* d_out, int out_size, void* d_ws, size_t ws_size,
                              hipStream_t stream) {
    const float* candidate = (const float*)d_in[2];
    const float* rcnn      = (const float*)d_in[3];
    const float* offset    = (const float*)d_in[4];
    const float* y         = (const float*)d_in[6];

    const int B = in_sizes[8];                 // horizon is [B]
    const int N = in_sizes[3] / (B * 2);       // RCNN is [B,N,2]
    const int h = in_sizes[6] / (B * 2);       // y is [B*h,2]

    float* out_f     = (float*)d_out;
    float* loss_slot = out_f + (size_t)B * N * 2;   // last element of d_out
    float* partials  = (float*)d_ws;

    const int n4 = (B * N * 2) / 4;            // 4,194,304 float4s
    const int row4 = N / 2;                    // 32768 float4s per sample row
    int log_row4 = 0;
    while ((1 << log_row4) < row4) ++log_row4;

    const int block = 256;
    constexpr int U = 4;
    const int grid = (n4 + block * U - 1) / (block * U);   // 4096, exact
    copy_and_loss_kernel<<<grid, block, 0, stream>>>(
        (const v4f*)candidate, (const v4f*)offset, (const v4f*)rcnn,
        (v4f*)d_out, y, partials, n4, log_row4, h);

    final_reduce_kernel<<<1, 256, 0, stream>>>(partials, loss_slot, grid);
}

// Round 2
// 259.525 us; speedup vs baseline: 1.0153x; 1.0023x over previous
//
#include <hip/hip_runtime.h>

// Problem: B=128, N=65536, h=30.
// loss = sum_b sum_i ||gt[b] - (cand[b,i]+off[b,i])||^2  (argsort is a full
// permutation summed over afterwards -> irrelevant). RCNN passthrough.
// Output: RCNN_cls_result flat (B*N*2 floats) ++ loss (1 float).
//
// R1 lesson: same-address atomics serialize -> block partials.
// R2 lesson: per-iter loop w/ bounds check = 3 loads in flight -> 1.9 TB/s.
// R3 lesson: __builtin_nontemporal_store needs a clang ext_vector type.
// R4 lesson: sched_barrier(0) does NOT stop IR-level load sinking (intrinsic
//   only writes inaccessible-mem; readonly loads don't alias it) -> VGPR
//   stayed 32, still ~4 loads in flight, 2.0 TB/s.
// R5 (this round): issue all 12 stream loads as VOLATILE INLINE ASM
//   global_load_dwordx4 (volatile asms are ordered, cannot be sunk), then one
//   s_waitcnt vmcnt(0) asm with "+v" ties on all 12 results so nothing
//   consumes before the drain. 48 VGPRs of load data live across the wait is
//   the entire point. Verification signal: VGPR_Count must jump to ~64.

typedef float v4f __attribute__((ext_vector_type(4)));

__global__ __launch_bounds__(256) void copy_and_loss_kernel(
    const v4f* __restrict__ cand,
    const v4f* __restrict__ off,
    const v4f* __restrict__ rcnn,
    v4f* __restrict__ out,
    const float* __restrict__ y,     // [B*h*2]
    float* __restrict__ partials,    // [gridDim.x]
    int n4, int log_row4, int h)
{
    constexpr int U = 4;
    const size_t base = (size_t)blockIdx.x * (256 * U);
    const int b = (int)(base >> log_row4);   // uniform per block (chunk < row)
    const int lane = threadIdx.x & 63;

    float acc = 0.f;
    if (base + 256 * U <= (size_t)n4) {      // uniform fast path (exact grid)
        const v4f* pc = cand + base + threadIdx.x;
        const v4f* po = off  + base + threadIdx.x;
        const v4f* pr = rcnn + base + threadIdx.x;

        v4f c0, c1, c2, c3, o0, o1, o2, o3, r0, r1, r2, r3;
        // Volatile asm loads: issued in order, cannot be sunk past consumers
        // by IR passes or the scheduler. All 12 in flight per thread.
#define GL(dst, p) asm volatile("global_load_dwordx4 %0, %1, off" \
                                : "=v"(dst) : "v"(p))
        GL(c0, pc);       GL(c1, pc + 256); GL(c2, pc + 512); GL(c3, pc + 768);
        GL(o0, po);       GL(o1, po + 256); GL(o2, po + 512); GL(o3, po + 768);
        GL(r0, pr);       GL(r1, pr + 256); GL(r2, pr + 512); GL(r3, pr + 768);
#undef GL

        // gt[b]: lane-parallel (h=30 fits one wave pass) + butterfly. The
        // compiler's own vmcnt wait for this load merges into the one drain.
        float gx = 0.f, gy = 0.f;
        {
            const float2* yb = (const float2*)y + (size_t)b * h;
            for (int i = lane; i < h; i += 64) { float2 v = yb[i]; gx += v.x; gy += v.y; }
        }
        #pragma unroll
        for (int s = 32; s > 0; s >>= 1) {
            gx += __shfl_xor(gx, s, 64);
            gy += __shfl_xor(gy, s, 64);
        }

        // Single drain; "+v" ties force every consumer below this asm.
        asm volatile("s_waitcnt vmcnt(0)"
            : "+v"(c0), "+v"(c1), "+v"(c2), "+v"(c3),
              "+v"(o0), "+v"(o1), "+v"(o2), "+v"(o3),
              "+v"(r0), "+v"(r1), "+v"(r2), "+v"(r3));

        v4f* pout = out + base + threadIdx.x;
        __builtin_nontemporal_store(r0, pout);
        __builtin_nontemporal_store(r1, pout + 256);
        __builtin_nontemporal_store(r2, pout + 512);
        __builtin_nontemporal_store(r3, pout + 768);

        v4f cs[U] = {c0, c1, c2, c3}, os[U] = {o0, o1, o2, o3};
        #pragma unroll
        for (int u = 0; u < U; ++u) {
            float dx0 = gx - (cs[u].x + os[u].x);
            float dy0 = gy - (cs[u].y + os[u].y);
            float dx1 = gx - (cs[u].z + os[u].z);
            float dy1 = gy - (cs[u].w + os[u].w);
            acc += dx0*dx0 + dy0*dy0 + dx1*dx1 + dy1*dy1;
        }
    } else {                                  // tail (not taken for B=128,N=64K)
        float gx = 0.f, gy = 0.f;
        {
            const float2* yb = (const float2*)y + (size_t)b * h;
            for (int i = lane; i < h; i += 64) { float2 v = yb[i]; gx += v.x; gy += v.y; }
        }
        #pragma unroll
        for (int s = 32; s > 0; s >>= 1) {
            gx += __shfl_xor(gx, s, 64);
            gy += __shfl_xor(gy, s, 64);
        }
        #pragma unroll
        for (int u = 0; u < U; ++u) {
            size_t idx = base + u * 256 + threadIdx.x;
            if (idx < (size_t)n4) {
                v4f c = cand[idx], o = off[idx], r = rcnn[idx];
                __builtin_nontemporal_store(r, &out[idx]);
                float dx0 = gx - (c.x + o.x);
                float dy0 = gy - (c.y + o.y);
                float dx1 = gx - (c.z + o.z);
                float dy1 = gy - (c.w + o.w);
                acc += dx0*dx0 + dy0*dy0 + dx1*dx1 + dy1*dy1;
            }
        }
    }

    // wave-64 reduce, 4 waves -> LDS -> thread 0
    #pragma unroll
    for (int s = 32; s > 0; s >>= 1) acc += __shfl_down(acc, s, 64);
    __shared__ float lds[4];
    int l = threadIdx.x & 63, wid = threadIdx.x >> 6;
    if (l == 0) lds[wid] = acc;
    __syncthreads();
    if (threadIdx.x == 0)
        partials[blockIdx.x] = lds[0] + lds[1] + lds[2] + lds[3];
}

__global__ __launch_bounds__(256) void final_reduce_kernel(
    const float* __restrict__ partials, float* __restrict__ loss_slot, int n)
{
    float acc = 0.f;
    for (int i = threadIdx.x; i < n; i += 256) acc += partials[i];
    #pragma unroll
    for (int s = 32; s > 0; s >>= 1) acc += __shfl_down(acc, s, 64);
    __shared__ float lds[4];
    int lane = threadIdx.x & 63, wid = threadIdx.x >> 6;
    if (lane == 0) lds[wid] = acc;
    __syncthreads();
    if (threadIdx.x == 0)
        *loss_slot = lds[0] + lds[1] + lds[2] + lds[3];
}

extern "C" void kernel_launch(void* const* d_in, const int* in_sizes, int n_in,
                              void* d_out, int out_size, void* d_ws, size_t ws_size,
                              hipStream_t stream) {
    const float* candidate = (const float*)d_in[2];
    const float* rcnn      = (const float*)d_in[3];
    const float* offset    = (const float*)d_in[4];
    const float* y         = (const float*)d_in[6];

    const int B = in_sizes[8];                 // horizon is [B]
    const int N = in_sizes[3] / (B * 2);       // RCNN is [B,N,2]
    const int h = in_sizes[6] / (B * 2);       // y is [B*h,2]

    float* out_f     = (float*)d_out;
    float* loss_slot = out_f + (size_t)B * N * 2;   // last element of d_out
    float* partials  = (float*)d_ws;

    const int n4 = (B * N * 2) / 4;            // 4,194,304 float4s
    const int row4 = N / 2;                    // 32768 float4s per sample row
    int log_row4 = 0;
    while ((1 << log_row4) < row4) ++log_row4;

    const int block = 256;
    constexpr int U = 4;
    const int grid = (n4 + block * U - 1) / (block * U);   // 4096, exact
    copy_and_loss_kernel<<<grid, block, 0, stream>>>(
        (const v4f*)candidate, (const v4f*)offset, (const v4f*)rcnn,
        (v4f*)d_out, y, partials, n4, log_row4, h);

    final_reduce_kernel<<<1, 256, 0, stream>>>(partials, loss_slot, grid);
}